// Round 10
// baseline (211.325 us; speedup 1.0000x reference)
//
#include <hip/hip_runtime.h>

#define NB 2048
#define NS 1024
#define NL 32

static __device__ __forceinline__ float fexp2(float x) {
#if __has_builtin(__builtin_amdgcn_exp2f)
  return __builtin_amdgcn_exp2f(x);
#else
  float r; asm("v_exp_f32 %0, %1" : "=v"(r) : "v"(x)); return r;
#endif
}
static __device__ __forceinline__ float flog2(float x) {
#if __has_builtin(__builtin_amdgcn_logf)
  return __builtin_amdgcn_logf(x);
#else
  float r; asm("v_log_f32 %0, %1" : "=v"(r) : "v"(x)); return r;
#endif
}

template<int K>
static __device__ __forceinline__ int roti(int x) {
  if constexpr (K == 0) return x;
  else return __builtin_amdgcn_update_dpp(0, x, 0x120 | K, 0xf, 0xf, true); // row_ror:K
}
template<int K>
static __device__ __forceinline__ float rotf(float x) {
  return __int_as_float(roti<K>(__float_as_int(x)));
}

// Raw permlane swap with s_nop hazard guards: gfx950 has a VALU-write ->
// permlane*_swap-read wait-state the compiler inserts for builtins but NOT
// inside inline asm (R6/R8's deterministic 2% error = stale operand reads).
// Returns x+y = part + part[pair(lane)] for the instruction's pairing.
static __device__ __forceinline__ float plswap16_sum(float part) {
  float x, y;
  asm volatile("v_mov_b32 %0, %2\n\t"
               "v_mov_b32 %1, %2\n\t"
               "s_nop 1\n\t"
               "v_permlane16_swap_b32 %0, %1\n\t"
               "s_nop 1"
               : "=&v"(x), "=&v"(y) : "v"(part));
  return x + y;
}
static __device__ __forceinline__ float plswap32_sum(float part) {
  float x, y;
  asm volatile("v_mov_b32 %0, %2\n\t"
               "v_mov_b32 %1, %2\n\t"
               "s_nop 1\n\t"
               "v_permlane32_swap_b32 %0, %1\n\t"
               "s_nop 1"
               : "=&v"(x), "=&v"(y) : "v"(part));
  return x + y;
}
static __device__ __forceinline__ int plswap16_partner(int lane) {
  int x, y;
  asm volatile("v_mov_b32 %0, %2\n\t"
               "v_mov_b32 %1, %2\n\t"
               "s_nop 1\n\t"
               "v_permlane16_swap_b32 %0, %1\n\t"
               "s_nop 1"
               : "=&v"(x), "=&v"(y) : "v"(lane));
  return x + y - lane;  // pair sum of lane indices minus self
}

// 16-term rotate/FMA tree: sum_k rot_k(p) * E[k], 4 chains of depth 4
static __device__ __forceinline__ float tree16(float p, const float* E) {
  float a0 = p * E[0];
  float a1 = rotf<1>(p) * E[1];
  float a2 = rotf<2>(p) * E[2];
  float a3 = rotf<3>(p) * E[3];
  a0 = fmaf(rotf<4>(p),  E[4],  a0);
  a1 = fmaf(rotf<5>(p),  E[5],  a1);
  a2 = fmaf(rotf<6>(p),  E[6],  a2);
  a3 = fmaf(rotf<7>(p),  E[7],  a3);
  a0 = fmaf(rotf<8>(p),  E[8],  a0);
  a1 = fmaf(rotf<9>(p),  E[9],  a1);
  a2 = fmaf(rotf<10>(p), E[10], a2);
  a3 = fmaf(rotf<11>(p), E[11], a3);
  a0 = fmaf(rotf<12>(p), E[12], a0);
  a1 = fmaf(rotf<13>(p), E[13], a1);
  a2 = fmaf(rotf<14>(p), E[14], a2);
  a3 = fmaf(rotf<15>(p), E[15], a3);
  return (a0 + a1) + (a2 + a3);
}

__global__ void zero_out_k(float* out) {
  if (threadIdx.x < 2) out[threadIdx.x] = 0.0f;
}

__global__ __launch_bounds__(64, 2)
void crf_fwd(const float* __restrict__ scores, const float* __restrict__ trans,
             const int* __restrict__ lens, const int* __restrict__ tags,
             float* __restrict__ out)
{
  constexpr float LOG2E = 1.4426950408889634f;
  constexpr float LN2   = 0.6931471805599453f;
  __shared__ float Tld[NL * NL];        // transition * log2e
  __shared__ float Emt[2][32 * NL];     // emit chunk double-buffer (32 rows)

  const int b    = blockIdx.x;
  const int lane = threadIdx.x;
  const int len  = lens[b];
  const int r = lane >> 4, c = lane & 15;
  const int labA = c + ((r & 1) << 4);         // label held in layout A (rows alternate halves)

  // --- calibrate permlane16_swap pairing (any odd<->even row pairing is OK) ---
  const int p16 = plswap16_partner(lane);
  // sane pairing: same column, opposite row parity (odd row <-> even row)
  const bool plOK = ((p16 & 15) == c) && ((((p16 >> 4) ^ r) & 1) == 1);
  // labB must be constant on ^16-combine pairs and balanced (2 rows each half).
  // [max(lane,partner) >= 48] distinguishes the two pairs for both possible
  // odd-even pairings; falls back to the shfl(^16) layout if !plOK.
  const int pmax = (lane > p16) ? lane : p16;
  const int labB = plOK ? (c + ((pmax >= 48) ? 16 : 0))
                        : (c + (((r >> 1) & 1) << 4));

  const float* sb = scores + (size_t)b * (NS * NL);

#define STAGE(BUFI, T0) do { \
    const float* gsrc_ = sb + (size_t)(T0) * NL; \
    _Pragma("unroll") \
    for (int k_ = 0; k_ < 4; ++k_) \
      __builtin_amdgcn_global_load_lds( \
        (const __attribute__((address_space(1))) void*)(gsrc_ + k_ * 256 + lane * 4), \
        (__attribute__((address_space(3))) void*)(&Emt[BUFI][k_ * 256]), 16, 0, 0); \
  } while (0)

  STAGE(0, 0);
  if (len > 32) STAGE(1, 32);

  #pragma unroll
  for (int k = 0; k < NL * NL; k += 64) Tld[k + lane] = trans[k + lane] * LOG2E;

  // E sets for both layouts, rotation-arrival order self-calibrated.
  // Step A: lane holds p_labA, computes output label labB. Step B: vice versa.
  float EA[16], EB[16];
#define CALA(K) EA[K] = fexp2(Tld[roti<K>(labA) * NL + labB]);
#define CALB(K) EB[K] = fexp2(Tld[roti<K>(labB) * NL + labA]);
  CALA(0)  CALA(1)  CALA(2)  CALA(3)  CALA(4)  CALA(5)  CALA(6)  CALA(7)
  CALA(8)  CALA(9)  CALA(10) CALA(11) CALA(12) CALA(13) CALA(14) CALA(15)
  CALB(0)  CALB(1)  CALB(2)  CALB(3)  CALB(4)  CALB(5)  CALB(6)  CALB(7)
  CALB(8)  CALB(9)  CALB(10) CALB(11) CALB(12) CALB(13) CALB(14) CALB(15)
#undef CALA
#undef CALB

  // init (layout A): alpha~0_j = T~[start=31][j] + log2e*emit0[j]; u = 2^(a0 - ls)
  float a0 = Tld[31 * NL + labA];
  asm volatile("s_waitcnt vmcnt(0)" ::: "memory");
  a0 = fmaf(Emt[0][labA], LOG2E, a0);
  float ls = __int_as_float(__builtin_amdgcn_readfirstlane(__float_as_int(a0)));
  float u = fexp2(a0 - ls);

  // emit lookahead: eA for odd times (A-steps, label labB), eB for even times (label labA)
  float eA = (len > 1) ? Emt[0][1 * NL + labB] : 0.0f;
  float eB = (len > 2) ? Emt[0][2 * NL + labA] : 0.0f;
  int buf = 0;
  bool endB = false;

  int t = 1;
  while (t + 1 < len) {
    if ((t & 3) == 1) {  // renorm every 4 steps: scale by 2^-exp(u_lane0)
      const int eb = __builtin_amdgcn_readfirstlane(__float_as_int(u));
      const int ex = (eb >> 23) - 127;
      ls += (float)ex;
      u *= __int_as_float((127 - ex) << 23);
    }
    const float wA = fexp2(eA * LOG2E);
    const float wB = fexp2(eB * LOG2E);
    // prefetch next pair's emits (consumed ~2 steps later)
    {
      const int tn = t + 2;                    // odd: never row 0
      if (tn < len) eA = Emt[buf][(tn & 31) * NL + labB];
    }
    {
      const int tn = t + 3;                    // even: handles chunk boundary
      if (tn < len) {
        const int row = tn & 31;
        if (row) {
          eB = Emt[buf][row * NL + labA];
        } else {
          asm volatile("s_waitcnt vmcnt(0) lgkmcnt(0)" ::: "memory");
          buf ^= 1;
          eB = Emt[buf][labA];
          if (tn + 32 < len) STAGE(buf ^ 1, tn + 32);
        }
      }
    }
    // step A (time t): combine over the calibrated ^16-pairing, layout A -> B
    {
      const float s = tree16(u, EA);
      u = (plOK ? plswap16_sum(s) : (s + __shfl_xor(s, 16))) * wA;
    }
    // step B (time t+1): combine halves (l^32), layout B -> A
    u = plswap32_sum(tree16(u, EB)) * wB;
    t += 2;
  }
  if (t < len) {  // leftover single A-step; state ends in layout B
    if ((t & 3) == 1) {
      const int eb = __builtin_amdgcn_readfirstlane(__float_as_int(u));
      const int ex = (eb >> 23) - 127;
      ls += (float)ex;
      u *= __int_as_float((127 - ex) << 23);
    }
    const float wA = fexp2(eA * LOG2E);
    const float s = tree16(u, EA);
    u = (plOK ? plswap16_sum(s) : (s + __shfl_xor(s, 16))) * wA;
    endB = true;
  }

  // unlabeled: ln2 * logsumexp2_j(alpha~_j + T~[j][end]); each j appears 2x -> -1
  const int elab = endB ? labB : labA;
  const float alpha = ls + flog2(u);
  float v = alpha + Tld[elab * NL + 30];
  float mm = v;
  #pragma unroll
  for (int w = 32; w; w >>= 1) mm = fmaxf(mm, __shfl_xor(mm, w));
  float ss = fexp2(v - mm);
  #pragma unroll
  for (int w = 32; w; w >>= 1) ss += __shfl_xor(ss, w);
  if (lane == 0) atomicAdd(out + 0, LN2 * (mm + flog2(ss) - 1.0f));

  // labeled score (scaled domain, *ln2 at end)
  const int* tb = tags + (size_t)b * NS;
  float lab = 0.0f;
  if (lane == 0) {
    const int tg0 = tb[0];
    lab += Tld[31 * NL + tg0] + LOG2E * sb[tg0];   // begin
    const int tgl = tb[len - 1];
    lab += Tld[tgl * NL + 30];                     // end
  }
  for (int t2 = 1 + lane; t2 < len; t2 += 64) {
    const int tp = tb[t2 - 1];
    const int tg = tb[t2];
    lab += Tld[tp * NL + tg] + LOG2E * sb[(size_t)t2 * NL + tg];
  }
  #pragma unroll
  for (int w = 32; w; w >>= 1) lab += __shfl_xor(lab, w);
  if (lane == 0) atomicAdd(out + 1, LN2 * lab);
#undef STAGE
}

extern "C" void kernel_launch(void* const* d_in, const int* in_sizes, int n_in,
                              void* d_out, int out_size, void* d_ws, size_t ws_size,
                              hipStream_t stream) {
  const float* scores = (const float*)d_in[0];
  const float* trans  = (const float*)d_in[1];
  const int*   lens   = (const int*)d_in[2];
  const int*   tags   = (const int*)d_in[3];
  float* out = (float*)d_out;

  zero_out_k<<<1, 64, 0, stream>>>(out);
  crf_fwd<<<NB, 64, 0, stream>>>(scores, trans, lens, tags, out);
}

// Round 11
// 161.656 us; speedup vs baseline: 1.3073x; 1.3073x over previous
//
#include <hip/hip_runtime.h>

#define NB 2048
#define NS 1024
#define NL 32

static __device__ __forceinline__ float fexp2(float x) {
#if __has_builtin(__builtin_amdgcn_exp2f)
  return __builtin_amdgcn_exp2f(x);
#else
  float r; asm("v_exp_f32 %0, %1" : "=v"(r) : "v"(x)); return r;
#endif
}
static __device__ __forceinline__ float flog2(float x) {
#if __has_builtin(__builtin_amdgcn_logf)
  return __builtin_amdgcn_logf(x);
#else
  float r; asm("v_log_f32 %0, %1" : "=v"(r) : "v"(x)); return r;
#endif
}

template<int K>
static __device__ __forceinline__ int roti(int x) {
  if constexpr (K == 0) return x;
  else return __builtin_amdgcn_update_dpp(0, x, 0x120 | K, 0xf, 0xf, true); // row_ror:K
}
template<int K>
static __device__ __forceinline__ float rotf(float x) {
  return __int_as_float(roti<K>(__float_as_int(x)));
}

// part + part[pair(lane)] via permlane swaps with s_nop hazard guards
// (validated R10: raw asm permlane needs explicit wait-states).
static __device__ __forceinline__ float plswap16_sum(float part) {
  float x, y;
  asm volatile("v_mov_b32 %0, %2\n\t"
               "v_mov_b32 %1, %2\n\t"
               "s_nop 1\n\t"
               "v_permlane16_swap_b32 %0, %1\n\t"
               "s_nop 1"
               : "=&v"(x), "=&v"(y) : "v"(part));
  return x + y;
}
static __device__ __forceinline__ float plswap32_sum(float part) {
  float x, y;
  asm volatile("v_mov_b32 %0, %2\n\t"
               "v_mov_b32 %1, %2\n\t"
               "s_nop 1\n\t"
               "v_permlane32_swap_b32 %0, %1\n\t"
               "s_nop 1"
               : "=&v"(x), "=&v"(y) : "v"(part));
  return x + y;
}
static __device__ __forceinline__ int plswap16_partner(int lane) {
  int x, y;
  asm volatile("v_mov_b32 %0, %2\n\t"
               "v_mov_b32 %1, %2\n\t"
               "s_nop 1\n\t"
               "v_permlane16_swap_b32 %0, %1\n\t"
               "s_nop 1"
               : "=&v"(x), "=&v"(y) : "v"(lane));
  return x + y - lane;
}

// 16-term rotate/FMA tree: sum_k rot_k(p) * E[k]
static __device__ __forceinline__ float tree16(float p, const float* E) {
  float a0 = p * E[0];
  float a1 = rotf<1>(p) * E[1];
  float a2 = rotf<2>(p) * E[2];
  float a3 = rotf<3>(p) * E[3];
  a0 = fmaf(rotf<4>(p),  E[4],  a0);
  a1 = fmaf(rotf<5>(p),  E[5],  a1);
  a2 = fmaf(rotf<6>(p),  E[6],  a2);
  a3 = fmaf(rotf<7>(p),  E[7],  a3);
  a0 = fmaf(rotf<8>(p),  E[8],  a0);
  a1 = fmaf(rotf<9>(p),  E[9],  a1);
  a2 = fmaf(rotf<10>(p), E[10], a2);
  a3 = fmaf(rotf<11>(p), E[11], a3);
  a0 = fmaf(rotf<12>(p), E[12], a0);
  a1 = fmaf(rotf<13>(p), E[13], a1);
  a2 = fmaf(rotf<14>(p), E[14], a2);
  a3 = fmaf(rotf<15>(p), E[15], a3);
  return (a0 + a1) + (a2 + a3);
}

__global__ void zero_out_k(float* out) {
  if (threadIdx.x < 2) out[threadIdx.x] = 0.0f;
}

__global__ __launch_bounds__(128, 2)
void crf_fwd(const float* __restrict__ scores, const float* __restrict__ trans,
             const int* __restrict__ lens, const int* __restrict__ tags,
             float* __restrict__ out)
{
  constexpr float LOG2E = 1.4426950408889634f;
  constexpr float LN2   = 0.6931471805599453f;
  __shared__ float Tld[NL * NL];
  __shared__ float Emt[2][2][32 * NL];   // [wave][dbuf][32 rows]
  float* slot = (float*)&Emt[0][0][0];   // 64 floats, reused AFTER chains (barrier-separated)

  const int b    = blockIdx.x;
  const int tid  = threadIdx.x;
  const int wid  = tid >> 6;
  const int lane = tid & 63;
  const int len  = lens[b];
  const int m    = len >> 1;            // forward computes alpha_m (m steps)
  const int nB   = len - 1 - m;         // backward computes beta_m (nB steps)
  const int r = lane >> 4, c = lane & 15;
  const int labA = c + ((r & 1) << 4);

  const int p16 = plswap16_partner(lane);
  const bool plOK = ((p16 & 15) == c) && ((((p16 >> 4) ^ r) & 1) == 1);
  const int pmax = (lane > p16) ? lane : p16;
  const int labB = plOK ? (c + ((pmax >= 48) ? 16 : 0))
                        : (c + (((r >> 1) & 1) << 4));

  const float* sb = scores + (size_t)b * (NS * NL);

#define STAGEW(W, BUFI, T0) do { \
    const float* gsrc_ = sb + (size_t)(T0) * NL; \
    _Pragma("unroll") \
    for (int k_ = 0; k_ < 4; ++k_) \
      __builtin_amdgcn_global_load_lds( \
        (const __attribute__((address_space(1))) void*)(gsrc_ + k_ * 256 + lane * 4), \
        (__attribute__((address_space(3))) void*)(&Emt[W][BUFI][k_ * 256]), 16, 0, 0); \
  } while (0)
#define WAITALL asm volatile("s_waitcnt vmcnt(0) lgkmcnt(0)" ::: "memory")

  int curC = 0, buf = 0;
  if (wid == 0) {
    STAGEW(0, 0, 0);
    if (m >= 32) STAGEW(0, 1, 32);
  } else if (nB > 0) {
    curC = (len - 1) >> 5;
    STAGEW(1, 0, curC * 32);
    if (curC >= 1 && curC * 32 - 1 >= m + 1) STAGEW(1, 1, (curC - 1) * 32);
  }

  for (int k = tid; k < NL * NL; k += 128) Tld[k] = trans[k] * LOG2E;
  __syncthreads();

  float u, ls;
  bool endB = false;

#define RENORM do { \
    const int eb_ = __builtin_amdgcn_readfirstlane(__float_as_int(u)); \
    const int ex_ = (eb_ >> 23) - 127; \
    ls += (float)ex_; \
    u *= __int_as_float((127 - ex_) << 23); \
  } while (0)
#define COMB16(S) (plOK ? plswap16_sum(S) : ((S) + __shfl_xor((S), 16)))

  if (wid == 0) {
    // ---------------- forward: alpha_0 .. alpha_m ----------------
    float EA[16], EB[16];
#define CALA(K) EA[K] = fexp2(Tld[roti<K>(labA) * NL + labB]);
#define CALB(K) EB[K] = fexp2(Tld[roti<K>(labB) * NL + labA]);
    CALA(0)  CALA(1)  CALA(2)  CALA(3)  CALA(4)  CALA(5)  CALA(6)  CALA(7)
    CALA(8)  CALA(9)  CALA(10) CALA(11) CALA(12) CALA(13) CALA(14) CALA(15)
    CALB(0)  CALB(1)  CALB(2)  CALB(3)  CALB(4)  CALB(5)  CALB(6)  CALB(7)
    CALB(8)  CALB(9)  CALB(10) CALB(11) CALB(12) CALB(13) CALB(14) CALB(15)
#undef CALA
#undef CALB
    float a0 = Tld[31 * NL + labA];            // T~[start][labA]
    WAITALL;
    a0 = fmaf(Emt[0][0][labA], LOG2E, a0);
    ls = __int_as_float(__builtin_amdgcn_readfirstlane(__float_as_int(a0)));
    u = fexp2(a0 - ls);

    float eA = (m >= 1) ? Emt[0][0][1 * NL + labB] : 0.0f;
    float eB = (m >= 2) ? Emt[0][0][2 * NL + labA] : 0.0f;
    buf = 0;
    int t = 1;
    while (t + 1 <= m) {
      if ((t & 3) == 1) RENORM;
      const float wAv = fexp2(eA * LOG2E);
      const float wBv = fexp2(eB * LOG2E);
      { const int tn = t + 2;                 // odd row, never chunk-start
        if (tn <= m) eA = Emt[0][buf][(tn & 31) * NL + labB]; }
      { const int tn = t + 3;
        if (tn <= m) {
          const int row = tn & 31;
          if (row) {
            eB = Emt[0][buf][row * NL + labA];
          } else {
            WAITALL; buf ^= 1;
            eB = Emt[0][buf][labA];
            if (tn + 32 <= m) STAGEW(0, buf ^ 1, tn + 32);
          }
        } }
      u = COMB16(tree16(u, EA)) * wAv;        // A-step: layout A -> B
      u = plswap32_sum(tree16(u, EB)) * wBv;  // B-step: layout B -> A
      t += 2;
    }
    if (t <= m) {                             // leftover A-step (m odd)
      if ((t & 3) == 1) RENORM;
      const float wAv = fexp2(eA * LOG2E);
      u = COMB16(tree16(u, EA)) * wAv;
      endB = true;
    }
  } else {
    // ---------------- backward: beta_{len-1} .. beta_m ----------------
    // beta step: u_out[labOUT] = sum_held E~[labOUT][held] * (w_{t+1}[held] * u[held])
    float EA[16], EB[16];                     // transposed-index calibration
#define CBA(K) EA[K] = fexp2(Tld[labB * NL + roti<K>(labA)]);
#define CBB(K) EB[K] = fexp2(Tld[labA * NL + roti<K>(labB)]);
    CBA(0)  CBA(1)  CBA(2)  CBA(3)  CBA(4)  CBA(5)  CBA(6)  CBA(7)
    CBA(8)  CBA(9)  CBA(10) CBA(11) CBA(12) CBA(13) CBA(14) CBA(15)
    CBB(0)  CBB(1)  CBB(2)  CBB(3)  CBB(4)  CBB(5)  CBB(6)  CBB(7)
    CBB(8)  CBB(9)  CBB(10) CBB(11) CBB(12) CBB(13) CBB(14) CBB(15)
#undef CBA
#undef CBB
    float a0 = Tld[labA * NL + 30];           // T~[labA][end]
    ls = __int_as_float(__builtin_amdgcn_readfirstlane(__float_as_int(a0)));
    u = fexp2(a0 - ls);

    if (nB > 0) {
      WAITALL;
      float eA = Emt[1][0][((len - 1) & 31) * NL + labA];  // step k=0 weight (held labA)
      float eB = 0.0f;
      if (nB > 1) {
        const int x = len - 2;
        if ((x >> 5) != curC) {
          WAITALL; buf ^= 1; curC--;
          if (curC >= 1 && curC * 32 - 1 >= m + 1) STAGEW(1, buf ^ 1, (curC - 1) * 32);
        }
        eB = Emt[1][buf][(x & 31) * NL + labB];
      }
      int k = 0;
      while (k + 1 < nB) {
        if ((k & 3) == 0) RENORM;
        const float wAv = fexp2(eA * LOG2E);
        const float wBv = fexp2(eB * LOG2E);
        { const int x = len - 3 - k;          // next A-step emit row (held labA)
          if (k + 2 < nB) {
            if ((x >> 5) != curC) {
              WAITALL; buf ^= 1; curC--;
              if (curC >= 1 && curC * 32 - 1 >= m + 1) STAGEW(1, buf ^ 1, (curC - 1) * 32);
            }
            eA = Emt[1][buf][(x & 31) * NL + labA];
          } }
        { const int x = len - 4 - k;          // next B-step emit row (held labB)
          if (k + 3 < nB) {
            if ((x >> 5) != curC) {
              WAITALL; buf ^= 1; curC--;
              if (curC >= 1 && curC * 32 - 1 >= m + 1) STAGEW(1, buf ^ 1, (curC - 1) * 32);
            }
            eB = Emt[1][buf][(x & 31) * NL + labB];
          } }
        u = COMB16(tree16(u * wAv, EA));         // A-step: layout A -> B
        u = plswap32_sum(tree16(u * wBv, EB));   // B-step: layout B -> A
        k += 2;
      }
      if (k < nB) {                              // leftover A-step (nB odd)
        if ((k & 3) == 0) RENORM;
        const float wAv = fexp2(eA * LOG2E);
        u = COMB16(tree16(u * wAv, EA));
        endB = true;
      }
    }
  }

  __syncthreads();   // chains done; Emt dead -> slot space valid
  {
    const int labX = endB ? labB : labA;
    slot[wid * 32 + labX] = ls + flog2(u);   // dup lanes write identical value
  }
  __syncthreads();

  if (wid == 0) {
    // Z = ln2 * LSE2_j(alphalog[j] + betalog[j])
    float v2 = (lane < 32) ? (slot[lane] + slot[32 + lane]) : -3.0e38f;
    float mm = v2;
    #pragma unroll
    for (int w = 32; w; w >>= 1) mm = fmaxf(mm, __shfl_xor(mm, w));
    float ssum = fexp2(v2 - mm);
    #pragma unroll
    for (int w = 32; w; w >>= 1) ssum += __shfl_xor(ssum, w);
    if (lane == 0) atomicAdd(out + 0, LN2 * (mm + flog2(ssum)));

    // labeled score
    const int* tb = tags + (size_t)b * NS;
    float lab = 0.0f;
    if (lane == 0) {
      const int tg0 = tb[0];
      lab += Tld[31 * NL + tg0] + LOG2E * sb[tg0];
      const int tgl = tb[len - 1];
      lab += Tld[tgl * NL + 30];
    }
    for (int t2 = 1 + lane; t2 < len; t2 += 64) {
      const int tp = tb[t2 - 1];
      const int tg = tb[t2];
      lab += Tld[tp * NL + tg] + LOG2E * sb[(size_t)t2 * NL + tg];
    }
    #pragma unroll
    for (int w = 32; w; w >>= 1) lab += __shfl_xor(lab, w);
    if (lane == 0) atomicAdd(out + 1, LN2 * lab);
  }
#undef STAGEW
#undef WAITALL
#undef RENORM
#undef COMB16
}

extern "C" void kernel_launch(void* const* d_in, const int* in_sizes, int n_in,
                              void* d_out, int out_size, void* d_ws, size_t ws_size,
                              hipStream_t stream) {
  const float* scores = (const float*)d_in[0];
  const float* trans  = (const float*)d_in[1];
  const int*   lens   = (const int*)d_in[2];
  const int*   tags   = (const int*)d_in[3];
  float* out = (float*)d_out;

  zero_out_k<<<1, 64, 0, stream>>>(out);
  crf_fwd<<<NB, 128, 0, stream>>>(scores, trans, lens, tags, out);
}